// Round 4
// baseline (579.388 us; speedup 1.0000x reference)
//
#include <hip/hip_runtime.h>
#include <cstdint>
#include <cstddef>

typedef _Float16 f16;
typedef _Float16 f16x8 __attribute__((ext_vector_type(8)));
typedef float f32x4 __attribute__((ext_vector_type(4)));

#define AS1 __attribute__((address_space(1)))
#define AS3 __attribute__((address_space(3)))

// async 16B global->LDS, per-lane source addr, LDS dst = wave-uniform base + lane*16
__device__ __forceinline__ void gl_lds16(const void* g, void* l) {
  __builtin_amdgcn_global_load_lds((AS1 void*)g, (AS3 void*)l, 16u, 0, 0u);
}

// c_tab[parity][a(tap)][i(conv-weight idx)] — folded FIR/upsample coefficients
__constant__ float c_tab[2][3][3] = {
  {{0.75f, 0.25f, 0.00f}, {0.25f, 0.75f, 0.75f}, {0.00f, 0.00f, 0.25f}},
  {{0.25f, 0.00f, 0.00f}, {0.75f, 0.75f, 0.25f}, {0.00f, 0.25f, 0.75f}}
};

// =====================================================================================
// Fused prep:
//  blocks [0,256):        build Et3[c8][ay3][ax3][jj1024][ic32] f16 from W (f32)
//  blocks [256,256+4224): fill Ah2[c8][n8][y66][x66][ic32] f16 (NCHW->chunk-major NHWC
//    + zeroed halo). NEW layout this round: ic-chunk-major so each gemm A-stage slab
//    (c, n, rows y0+ay..y0+ay+3) is ONE contiguous 16896-B run -> coalesced staging.
// =====================================================================================
__global__ __launch_bounds__(256) void prep_k(const float* __restrict__ W,
                                              const float* __restrict__ In,
                                              f16* __restrict__ Et,
                                              f16* __restrict__ Ah) {
  const int b = blockIdx.x;
  const int tid = threadIdx.x;
  if (b < 256) {
    // ---- Et3 build ----
    const int oc = b;
    const int ic = tid;
    const int c = ic >> 5, icl = ic & 31;
    float w[9];
    const float* wp = W + ((size_t)oc * 256 + ic) * 9;
#pragma unroll
    for (int t = 0; t < 9; ++t) w[t] = wp[t];
#pragma unroll
    for (int py = 0; py < 2; ++py)
#pragma unroll
      for (int px = 0; px < 2; ++px) {
        const int jj = oc * 4 + py * 2 + px;
#pragma unroll
        for (int ay = 0; ay < 3; ++ay)
#pragma unroll
          for (int ax = 0; ax < 3; ++ax) {
            float s = 0.f;
#pragma unroll
            for (int iy = 0; iy < 3; ++iy)
#pragma unroll
              for (int ix = 0; ix < 3; ++ix)
                s += w[iy * 3 + ix] * c_tab[py][ay][iy] * c_tab[px][ax][ix];
            Et[((size_t)(((c * 3 + ay) * 3 + ax) * 1024 + jj)) * 32 + icl] = (f16)s;
          }
      }
  } else {
    // ---- Ah2 fill: [c8][n8][y66][x66][ic32] ----
    const int bid2 = b - 256;
    const int icc = bid2 & 7;      // = c chunk
    const int v = bid2 >> 3;       // 0..527
    const int n = v / 66;
    const int yp = v - n * 66;     // y' in 0..65
    const int icl = tid & 31, x8 = tid >> 5;
    f16* rowbase = Ah + (((size_t)(icc * 8 + n) * 66 + yp) * 66) * 32;
    if (yp == 0 || yp == 65) {
      // full halo row -> zeros
#pragma unroll
      for (int i = 0; i < 9; ++i) {
        const int xp = i * 8 + x8;
        if (xp < 66) rowbase[(size_t)xp * 32 + icl] = (f16)0.f;
      }
    } else {
      const int y = yp - 1;
      __shared__ float tile[32][65];  // +1 pad: write-phase stride-65 reads, no conflicts
      const int xl = tid & 63, icl4 = tid >> 6;
      const float* src = In + (((size_t)(n * 256 + icc * 32)) * 64 + y) * 64;
#pragma unroll
      for (int i = 0; i < 8; ++i) {
        const int icl_ = i * 4 + icl4;
        tile[icl_][xl] = src[(size_t)icl_ * 4096 + xl];
      }
      __syncthreads();
      f16* dst = rowbase + 32;  // x'=1
#pragma unroll
      for (int i = 0; i < 8; ++i) {
        const int x = i * 8 + x8;
        dst[(size_t)x * 32 + icl] = (f16)tile[icl][x];
      }
      if (x8 == 0) {  // halo columns x'=0 and x'=65
        rowbase[icl] = (f16)0.f;
        rowbase[(size_t)65 * 32 + icl] = (f16)0.f;
      }
    }
  }
}

// =====================================================================================
// Implicit-GEMM conv, 256x256-tile 8-wave WAVE-STAGGERED schedule.
//   M=32768 x N=1024 x K=2304 = 24 stages (c,ay) x 3 ax-phases (K=32 each).
//   8 waves (2m x 4n), wave tile 128x64; LDS dbuf 132 KB; 1 block/CU, 2 waves/SIMD.
//
// NEW this round — cross-wave anti-phase ("stagger"): the 8 waves split into two
// 4-wave groups; the shifted group executes ONE extra s_barrier before the loop (and
// one fewer after). Barrier instances pair by count, so in every global barrier
// interval one group issues its 12 ds_reads (+staging) while the other runs its 32
// MFMAs — LDS pipe (~576 cyc) and matrix pipe (~620 cyc) overlap instead of
// alternating (rounds 0-3 all alternated => all ~200 µs; serialized-pipes model).
// Coloring (wave ^ (wave>>2)) & 1 puts one wave of each group on every SIMD under
// both plausible wave->SIMD mappings; m114: MFMA and VALU/LDS from different waves
// co-issue. Hazards under stagger:
//   WAR (read -> staging overwrite): last reader's lgkmcnt(0) precedes the barrier
//     that precedes the overwriter's gl_lds issue (proven per-interval).
//   RAW (staging -> read): per-group vmcnt(0) — after reads for shifted, after MFMAs
//     for unshifted — both before the barrier preceding the first read of the newly
//     staged buffer (>=4 intervals of load cover).
//   Barrier counts: unshifted barP+144+tail=146, shifted barP+barS+144=146 — match.
// Bank-conflict-free XOR swizzle retained (0 conflicts measured): reads
//   o ^= ((o>>7)&3)<<4; staging pre-swizzles the per-lane GLOBAL source granule.
// =====================================================================================
__global__ __launch_bounds__(512, 2) void gemm_k(const f16* __restrict__ Ah,
                                                 const f16* __restrict__ Et,
                                                 const float* __restrict__ bias,
                                                 float* __restrict__ out) {
  __shared__ __align__(256) f16 lA[2][8448];   // [buf][r4][x66][ic32]    2 x 16896 B
  __shared__ __align__(256) f16 lB[2][24576];  // [buf][ax3][jj256][ic32] 2 x 49152 B
  const int tid = threadIdx.x;
  const int wave = tid >> 6;     // 0..7
  const int lane = tid & 63;
  const int shifted = (wave ^ (wave >> 2)) & 1;  // stagger group (bichromatic per SIMD)
  // XCD-aware bijective swizzle: 512 blocks, 512%8==0.
  const int bid = (blockIdx.x & 7) * 64 + (blockIdx.x >> 3);
  const int nt = bid & 3;        // 4 jj-tiles of 256
  const int mt = bid >> 2;       // 128 m-tiles of 256
  const int m0 = mt * 256;
  const int jj0 = nt * 256;
  const int n = m0 >> 12;            // image
  const int y0 = (m0 >> 6) & 63;     // 0,4,..,60; tile covers y0..y0+3, x 0..63

  // ---- staging per-lane constants (stage-invariant) ----
  // hig: source-side companion of the read swizzle (granule bits[1:0] ^= dst bits[8:7]).
  const int hig = (lane & 3) ^ ((lane >> 3) & 3);
  // A slab is contiguous 16896 B (chunk-major Ah2): 16 x 1KB slots + 512-B tail.
  int goA[2];
#pragma unroll
  for (int i = 0; i < 2; ++i)
    goA[i] = (wave * 2 + i) * 1024 + (lane >> 2) * 64 + hig * 16;
  // tail bytes 16384..16895: dst = 16384 + wave*64 + lane*16 (lanes 0..3)
  // dst bits[8:7] = wave>>1 -> source granule lane ^ (wave>>1).
  const int goAt = 16384 + wave * 64 + ((lane ^ (wave >> 1)) & 3) * 16;
  // B: 48 x 1KB slots; slot t = wave + 8*j: ax = t>>4, 16-jj sub-slab = t&15.
  int goB[6];
#pragma unroll
  for (int j = 0; j < 6; ++j) {
    const int t = wave + 8 * j;
    const int ax = t >> 4, jsl = t & 15;
    goB[j] = ax * 65536 + (jsl * 16 + (lane >> 2)) * 64 + hig * 16;
  }
  char* const lAb = (char*)lA;
  char* const lBb = (char*)lB;

  // ---- compute-side per-lane constants ----
  const int wm = wave >> 2, wn = wave & 3;  // 2m x 4n wave grid; wave tile 128m x 64jj
  const int lr = lane & 15;
  const int hi16 = (lane >> 4) * 16;
  int rdA0[8];
#pragma unroll
  for (int mi = 0; mi < 8; ++mi)
    rdA0[mi] = ((wm * 2 + (mi >> 2)) * 66 + (mi & 3) * 16 + lr) * 64 + hi16;  // unswizzled
  int rdBs[4];
#pragma unroll
  for (int ni = 0; ni < 4; ++ni) {
    const int o = (wn * 64 + ni * 16 + lr) * 64 + hi16;
    rdBs[ni] = o ^ (((o >> 7) & 3) << 4);
  }

  // A stage base (chunk-major): c=0, rows start y0 (+ay per stage); row = 4224 B.
  const char* const aBase = (const char*)Ah + ((size_t)n * 66 + y0) * 4224;
  const char* const bE = (const char*)Et + (size_t)jj0 * 64;

  const f32x4 vzero = {0.f, 0.f, 0.f, 0.f};
  f32x4 acc[8][4];
#pragma unroll
  for (int i = 0; i < 8; ++i)
#pragma unroll
    for (int j = 0; j < 4; ++j) acc[i][j] = vzero;

  // ---- prologue: stage 0 (c=0,ay=0) into buffer 0; cold drain ----
  {
    gl_lds16(aBase + goA[0], lAb + (wave * 2 + 0) * 1024);
    gl_lds16(aBase + goA[1], lAb + (wave * 2 + 1) * 1024);
    if (lane < 4) gl_lds16(aBase + goAt, lAb + 16384 + wave * 64);
#pragma unroll
    for (int j = 0; j < 6; ++j) gl_lds16(bE + goB[j], lBb + (wave + 8 * j) * 1024);
  }
  asm volatile("s_waitcnt vmcnt(0)" ::: "memory");
  __builtin_amdgcn_s_barrier();               // barP
  if (shifted) __builtin_amdgcn_s_barrier();  // barS: one-interval stagger shift

  const char* aPn = aBase + 4224;    // stage 1 source (c=0, ay=1): +1 row
  const char* bPn = bE + 196608;     // (c*3+ay) stride in Et3
  int ayn = 1;

#pragma unroll 1
  for (int t = 0; t < 24; ++t) {
    const int p = t & 1;
    const char* sA = lAb + p * 16896;
    const char* sB = lBb + p * 49152;

#pragma unroll
    for (int ax = 0; ax < 3; ++ax) {
      // --- read interval: 12 fragment ds_reads (overlaps partner group's MFMAs) ---
      f16x8 af[8], bf[4];
#pragma unroll
      for (int mi = 0; mi < 8; ++mi) {
        const int oa = rdA0[mi] + ax * 64;
        const int sw = oa ^ (((oa >> 7) & 3) << 4);
        af[mi] = *(const f16x8*)(sA + sw);
      }
#pragma unroll
      for (int ni = 0; ni < 4; ++ni)
        bf[ni] = *(const f16x8*)(sB + ax * 16384 + rdBs[ni]);

      // --- staging issue for stage t+1 (in this wave's read interval of (t,0)) ---
      if (ax == 0 && t < 23) {
        char* dA = lAb + (p ^ 1) * 16896;
        char* dB = lBb + (p ^ 1) * 49152;
        gl_lds16(aPn + goA[0], dA + (wave * 2 + 0) * 1024);
        gl_lds16(aPn + goA[1], dA + (wave * 2 + 1) * 1024);
        if (lane < 4) gl_lds16(aPn + goAt, dA + 16384 + wave * 64);
#pragma unroll
        for (int j = 0; j < 6; ++j) gl_lds16(bPn + goB[j], dB + (wave + 8 * j) * 1024);
        bPn += 196608;
        if (ayn == 2) { aPn += 2221824; ayn = 0; }  // c++: +2230272 - 2*4224
        else          { aPn += 4224; ++ayn; }
      }

      // own reads complete before the barrier (WAR fence for partner's staging)
      asm volatile("s_waitcnt lgkmcnt(0)" ::: "memory");
      // RAW drain for next stage's buffer: shifted group drains here (its interval
      // ends at the same global barrier as unshifted's post-MFMA drain below).
      if (shifted && ax == 2 && t < 23)
        asm volatile("s_waitcnt vmcnt(0)" ::: "memory");
      __builtin_amdgcn_s_barrier();
      __builtin_amdgcn_sched_barrier(0);

      // --- MFMA interval: partner group is reading now ---
      __builtin_amdgcn_s_setprio(1);
#pragma unroll
      for (int mi = 0; mi < 8; ++mi)
#pragma unroll
        for (int ni = 0; ni < 4; ++ni)
          acc[mi][ni] = __builtin_amdgcn_mfma_f32_16x16x32_f16(af[mi], bf[ni],
                                                               acc[mi][ni], 0, 0, 0);
      __builtin_amdgcn_s_setprio(0);

      if (!shifted && ax == 2 && t < 23)
        asm volatile("s_waitcnt vmcnt(0)" ::: "memory");
      __builtin_amdgcn_s_barrier();
      __builtin_amdgcn_sched_barrier(0);
    }
  }
  if (!shifted) __builtin_amdgcn_s_barrier();  // balance: pairs with shifted's last bar

  // ---- epilogue: C frag layout col=lane&15 (jj), row=(lane>>4)*4+v (m) ----
#pragma unroll
  for (int ni = 0; ni < 4; ++ni) {
    const int jj = jj0 + wn * 64 + ni * 16 + lr;
    const int oc = jj >> 2;
    const int py = (jj >> 1) & 1, px = jj & 1;
    const float bv = bias[oc];
#pragma unroll
    for (int mi = 0; mi < 8; ++mi) {
      const int y = y0 + wm * 2 + (mi >> 2);
      const int oy = 2 * y + py;
      const int xb = (mi & 3) * 16 + ((lane >> 4) << 2);
      float* orow = out + ((size_t)(n * 256 + oc) * 128 + oy) * 128;
#pragma unroll
      for (int v = 0; v < 4; ++v) {
        orow[2 * (xb + v) + px] = acc[mi][ni][v] + bv;
      }
    }
  }
}

// ---------------- fallback (ws too small): direct, slow, correct ---------------------
__global__ __launch_bounds__(256) void fallback_k(const float* __restrict__ In,
                                                  const float* __restrict__ W,
                                                  const float* __restrict__ bias,
                                                  float* __restrict__ out) {
  const size_t idx = (size_t)blockIdx.x * 256 + threadIdx.x;
  const int ox = (int)(idx & 127), oy = (int)((idx >> 7) & 127);
  const int oc = (int)((idx >> 14) & 255);
  const int n = (int)(idx >> 22);
  const int px = ox & 1, py = oy & 1;
  const int x = ox >> 1, y = oy >> 1;
  float cy[3][3], cx[3][3];
#pragma unroll
  for (int a = 0; a < 3; ++a)
#pragma unroll
    for (int i = 0; i < 3; ++i) {
      cy[a][i] = c_tab[py][a][i];
      cx[a][i] = c_tab[px][a][i];
    }
  float acc = 0.f;
  const float* wbase = W + (size_t)oc * 2304;
  for (int ic = 0; ic < 256; ++ic) {
    const float* ib = In + (((size_t)(n * 256 + ic)) * 64 + y) * 64 + x;
    float pin[3][3];
#pragma unroll
    for (int ay = 0; ay < 3; ++ay) {
      const int yy = y + ay - 1;
#pragma unroll
      for (int ax = 0; ax < 3; ++ax) {
        const int xx = x + ax - 1;
        pin[ay][ax] = (yy >= 0 && yy < 64 && xx >= 0 && xx < 64)
                          ? ib[(ay - 1) * 64 + (ax - 1)] : 0.f;
      }
    }
    const float* w = wbase + ic * 9;
    float U[3][3];
#pragma unroll
    for (int ay = 0; ay < 3; ++ay)
#pragma unroll
      for (int ix = 0; ix < 3; ++ix)
        U[ay][ix] = cx[0][ix] * pin[ay][0] + cx[1][ix] * pin[ay][1] + cx[2][ix] * pin[ay][2];
#pragma unroll
    for (int iy = 0; iy < 3; ++iy)
#pragma unroll
      for (int ix = 0; ix < 3; ++ix) {
        const float V = cy[0][iy] * U[0][ix] + cy[1][iy] * U[1][ix] + cy[2][iy] * U[2][ix];
        acc += w[iy * 3 + ix] * V;
      }
  }
  out[idx] = acc + bias[oc];
}

extern "C" void kernel_launch(void* const* d_in, const int* in_sizes, int n_in,
                              void* d_out, int out_size, void* d_ws, size_t ws_size,
                              hipStream_t stream) {
  const float* In = (const float*)d_in[0];    // [8][256][64][64]
  const float* W = (const float*)d_in[1];     // [256][256][3][3]
  const float* bias = (const float*)d_in[2];  // [256]
  float* out = (float*)d_out;                 // [8][256][128][128]

  const size_t E_BYTES = (size_t)1024 * 2304 * 2;       // 4,718,592
  const size_t A_BYTES = (size_t)8 * 66 * 66 * 256 * 2; // 17,842,176

  if (ws_size >= E_BYTES + A_BYTES) {
    f16* Et = (f16*)d_ws;
    f16* Ah = (f16*)((char*)d_ws + E_BYTES);
    prep_k<<<256 + 4224, 256, 0, stream>>>(W, In, Et, Ah);
    gemm_k<<<512, 512, 0, stream>>>(Ah, Et, bias, out);
  } else {
    fallback_k<<<131072, 256, 0, stream>>>(In, W, bias, out);
  }
}

// Round 5
// 314.684 us; speedup vs baseline: 1.8412x; 1.8412x over previous
//
#include <hip/hip_runtime.h>
#include <cstdint>
#include <cstddef>

typedef _Float16 f16;
typedef _Float16 f16x8 __attribute__((ext_vector_type(8)));
typedef float f32x4 __attribute__((ext_vector_type(4)));

#define AS1 __attribute__((address_space(1)))
#define AS3 __attribute__((address_space(3)))

// async 16B global->LDS, per-lane source addr, LDS dst = wave-uniform base + lane*16
__device__ __forceinline__ void gl_lds16(const void* g, void* l) {
  __builtin_amdgcn_global_load_lds((AS1 void*)g, (AS3 void*)l, 16u, 0, 0u);
}

// c_tab[parity][a(tap)][i(conv-weight idx)] — folded FIR/upsample coefficients
__constant__ float c_tab[2][3][3] = {
  {{0.75f, 0.25f, 0.00f}, {0.25f, 0.75f, 0.75f}, {0.00f, 0.00f, 0.25f}},
  {{0.25f, 0.00f, 0.00f}, {0.75f, 0.75f, 0.25f}, {0.00f, 0.25f, 0.75f}}
};

// =====================================================================================
// Fused prep (unchanged from round 4):
//  blocks [0,256):        build Et3[c8][ay3][ax3][jj1024][ic32] f16 from W (f32)
//  blocks [256,256+4224): fill Ah2[c8][n8][y66][x66][ic32] f16 (chunk-major NHWC +
//    zeroed halo) -> each gemm A-stage slab is ONE contiguous 16896-B run.
// =====================================================================================
__global__ __launch_bounds__(256) void prep_k(const float* __restrict__ W,
                                              const float* __restrict__ In,
                                              f16* __restrict__ Et,
                                              f16* __restrict__ Ah) {
  const int b = blockIdx.x;
  const int tid = threadIdx.x;
  if (b < 256) {
    // ---- Et3 build ----
    const int oc = b;
    const int ic = tid;
    const int c = ic >> 5, icl = ic & 31;
    float w[9];
    const float* wp = W + ((size_t)oc * 256 + ic) * 9;
#pragma unroll
    for (int t = 0; t < 9; ++t) w[t] = wp[t];
#pragma unroll
    for (int py = 0; py < 2; ++py)
#pragma unroll
      for (int px = 0; px < 2; ++px) {
        const int jj = oc * 4 + py * 2 + px;
#pragma unroll
        for (int ay = 0; ay < 3; ++ay)
#pragma unroll
          for (int ax = 0; ax < 3; ++ax) {
            float s = 0.f;
#pragma unroll
            for (int iy = 0; iy < 3; ++iy)
#pragma unroll
              for (int ix = 0; ix < 3; ++ix)
                s += w[iy * 3 + ix] * c_tab[py][ay][iy] * c_tab[px][ax][ix];
            Et[((size_t)(((c * 3 + ay) * 3 + ax) * 1024 + jj)) * 32 + icl] = (f16)s;
          }
      }
  } else {
    // ---- Ah2 fill: [c8][n8][y66][x66][ic32] ----
    const int bid2 = b - 256;
    const int icc = bid2 & 7;      // = c chunk
    const int v = bid2 >> 3;       // 0..527
    const int n = v / 66;
    const int yp = v - n * 66;     // y' in 0..65
    const int icl = tid & 31, x8 = tid >> 5;
    f16* rowbase = Ah + (((size_t)(icc * 8 + n) * 66 + yp) * 66) * 32;
    if (yp == 0 || yp == 65) {
      // full halo row -> zeros
#pragma unroll
      for (int i = 0; i < 9; ++i) {
        const int xp = i * 8 + x8;
        if (xp < 66) rowbase[(size_t)xp * 32 + icl] = (f16)0.f;
      }
    } else {
      const int y = yp - 1;
      __shared__ float tile[32][65];  // +1 pad: write-phase stride-65 reads, no conflicts
      const int xl = tid & 63, icl4 = tid >> 6;
      const float* src = In + (((size_t)(n * 256 + icc * 32)) * 64 + y) * 64;
#pragma unroll
      for (int i = 0; i < 8; ++i) {
        const int icl_ = i * 4 + icl4;
        tile[icl_][xl] = src[(size_t)icl_ * 4096 + xl];
      }
      __syncthreads();
      f16* dst = rowbase + 32;  // x'=1
#pragma unroll
      for (int i = 0; i < 8; ++i) {
        const int x = i * 8 + x8;
        dst[(size_t)x * 32 + icl] = (f16)tile[icl][x];
      }
      if (x8 == 0) {  // halo columns x'=0 and x'=65
        rowbase[icl] = (f16)0.f;
        rowbase[(size_t)65 * 32 + icl] = (f16)0.f;
      }
    }
  }
}

// =====================================================================================
// Implicit-GEMM conv, 256x256-tile, 8 waves (2m x 4n), wave tile 128x64.
//   M=32768 x N=1024, K = 24 stages (c,ay) x 3 ax-phases (K=32 ic each).
//   LDS dbuf 132 KB (A 2x16.9K, B 2x49.2K); 1 block/CU, 2 waves/SIMD.
//
// ROUND 5 — UNPINNED schedule (rounds 0-3 all ~200us / 33-36% MfmaUtil shared one
// thing: explicit lgkmcnt(0)+sched_barrier pins before every MFMA cluster = full LDS
// drain per phase; m141/common-mistake-5 says pins defeat the compiler's fine-grained
// lgkmcnt(4/3/1/0) scheduling. Stagger (round 4) reverted: 2.3x regression.)
//   Per stage t: ONE vmcnt(0) (drains staging issued a full stage ago -> free) +
//   ONE s_barrier + sched_barrier(0). Interior is compiler-scheduled, hand-pipelined
//   one phase ahead with static register sets (rule 20):
//     reads(ax0) -> staging issue(t+1) -> reads(ax1) -> MFMA(0) -> reads(ax2)
//     -> MFMA(1) -> MFMA(2)
//   No lgkmcnt asm: the compiler inserts counted waits, so MFMAs start when their
//   operands land and next-phase read latency hides under matrix-pipe execution.
// Hazards (re-derived): WAR — every ds_read of buf q is consumed by an MFMA issued
//   before that wave's barrier arrival (in-order issue + compiler lgkm waits), and
//   staging into q is issued only after the barrier => safe with ONE barrier/stage.
//   RAW — staging loads drained by next stage-top vmcnt(0) before any read of the
//   staged buffer (>= full stage of cover; nothing else in VM flight).
// Bank-conflict-free XOR swizzle retained (0 conflicts measured): reads
//   o ^= ((o>>7)&3)<<4; staging pre-swizzles the per-lane GLOBAL source granule.
// =====================================================================================
__global__ __launch_bounds__(512, 2) void gemm_k(const f16* __restrict__ Ah,
                                                 const f16* __restrict__ Et,
                                                 const float* __restrict__ bias,
                                                 float* __restrict__ out) {
  __shared__ __align__(256) f16 lA[2][8448];   // [buf][r4][x66][ic32]    2 x 16896 B
  __shared__ __align__(256) f16 lB[2][24576];  // [buf][ax3][jj256][ic32] 2 x 49152 B
  const int tid = threadIdx.x;
  const int wave = tid >> 6;     // 0..7
  const int lane = tid & 63;
  // XCD-aware bijective swizzle: 512 blocks, 512%8==0.
  const int bid = (blockIdx.x & 7) * 64 + (blockIdx.x >> 3);
  const int nt = bid & 3;        // 4 jj-tiles of 256
  const int mt = bid >> 2;       // 128 m-tiles of 256
  const int m0 = mt * 256;
  const int jj0 = nt * 256;
  const int n = m0 >> 12;            // image
  const int y0 = (m0 >> 6) & 63;     // 0,4,..,60; tile covers y0..y0+3, x 0..63

  // ---- staging per-lane constants (stage-invariant) ----
  // hig: source-side companion of the read swizzle (granule bits[1:0] ^= dst bits[8:7]).
  const int hig = (lane & 3) ^ ((lane >> 3) & 3);
  // A slab contiguous 16896 B: 16 x 1KB slots (2/wave) + 512-B tail (4 lanes x 8 waves).
  int goA[2];
#pragma unroll
  for (int i = 0; i < 2; ++i)
    goA[i] = (wave * 2 + i) * 1024 + (lane >> 2) * 64 + hig * 16;
  // tail: dst = 16384 + wave*64 + lane*16 (lanes 0..3); dst bits[8:7] = wave>>1
  // -> source granule lane ^ (wave>>1).
  const int goAt = 16384 + wave * 64 + ((lane ^ (wave >> 1)) & 3) * 16;
  // B: 48 x 1KB slots; slot t = wave + 8*j: ax = t>>4, 16-jj sub-slab = t&15.
  int goB[6];
#pragma unroll
  for (int j = 0; j < 6; ++j) {
    const int t = wave + 8 * j;
    const int ax = t >> 4, jsl = t & 15;
    goB[j] = ax * 65536 + (jsl * 16 + (lane >> 2)) * 64 + hig * 16;
  }
  char* const lAb = (char*)lA;
  char* const lBb = (char*)lB;

  // ---- compute-side per-lane constants ----
  const int wm = wave >> 2, wn = wave & 3;  // 2m x 4n wave grid; wave tile 128m x 64jj
  const int lr = lane & 15;
  const int hi16 = (lane >> 4) * 16;
  int rdA0[8];
#pragma unroll
  for (int mi = 0; mi < 8; ++mi)
    rdA0[mi] = ((wm * 2 + (mi >> 2)) * 66 + (mi & 3) * 16 + lr) * 64 + hi16;  // unswizzled
  int rdBs[4];
#pragma unroll
  for (int ni = 0; ni < 4; ++ni) {
    const int o = (wn * 64 + ni * 16 + lr) * 64 + hi16;
    rdBs[ni] = o ^ (((o >> 7) & 3) << 4);  // +ax*16384 preserves bits[8:0] -> still valid
  }

  // A stage base (chunk-major): c=0, rows start y0 (+ay per stage); row = 4224 B.
  const char* const aBase = (const char*)Ah + ((size_t)n * 66 + y0) * 4224;
  const char* const bE = (const char*)Et + (size_t)jj0 * 64;

  const f32x4 vzero = {0.f, 0.f, 0.f, 0.f};
  f32x4 acc[8][4];
#pragma unroll
  for (int i = 0; i < 8; ++i)
#pragma unroll
    for (int j = 0; j < 4; ++j) acc[i][j] = vzero;

  // ---- prologue: issue stage 0 (c=0,ay=0) into buffer 0 (drained at t=0 loop top) ----
  {
    gl_lds16(aBase + goA[0], lAb + (wave * 2 + 0) * 1024);
    gl_lds16(aBase + goA[1], lAb + (wave * 2 + 1) * 1024);
    if (lane < 4) gl_lds16(aBase + goAt, lAb + 16384 + wave * 64);
#pragma unroll
    for (int j = 0; j < 6; ++j) gl_lds16(bE + goB[j], lBb + (wave + 8 * j) * 1024);
  }

  const char* aPn = aBase + 4224;    // stage 1 source (c=0, ay=1): +1 row
  const char* bPn = bE + 196608;     // (c*3+ay) stride in Et3
  int ayn = 1;

#define LOADF(AF, BF, AX)                                                       \
  _Pragma("unroll")                                                             \
  for (int mi = 0; mi < 8; ++mi) {                                              \
    const int oa = rdA0[mi] + (AX) * 64;                                        \
    const int sw = oa ^ (((oa >> 7) & 3) << 4);                                 \
    AF[mi] = *(const f16x8*)(sA + sw);                                          \
  }                                                                             \
  _Pragma("unroll")                                                             \
  for (int ni = 0; ni < 4; ++ni)                                                \
    BF[ni] = *(const f16x8*)(sB + (AX) * 16384 + rdBs[ni]);

#define MFMAC(AF, BF)                                                           \
  _Pragma("unroll")                                                             \
  for (int mi = 0; mi < 8; ++mi)                                                \
    _Pragma("unroll")                                                           \
    for (int ni = 0; ni < 4; ++ni)                                              \
      acc[mi][ni] =                                                             \
          __builtin_amdgcn_mfma_f32_16x16x32_f16(AF[mi], BF[ni], acc[mi][ni], 0, 0, 0);

#pragma unroll 1
  for (int t = 0; t < 24; ++t) {
    const int p = t & 1;
    const char* sA = lAb + p * 16896;
    const char* sB = lBb + p * 49152;

    // stage boundary: drain last stage's staging (issued a full stage ago -> ~free),
    // make buf[p] visible; sched_barrier pins nothing inside the stage, only the edge.
    asm volatile("s_waitcnt vmcnt(0)" ::: "memory");
    __builtin_amdgcn_s_barrier();
    __builtin_amdgcn_sched_barrier(0);

    f16x8 afA[8], bfA[4], afB[8], bfB[4];
    LOADF(afA, bfA, 0);

    // staging issue for stage t+1 into buf[p^1] (readers of p^1 finished: their MFMAs
    // issued before the barrier above). Early issue = max latency cover.
    if (t < 23) {
      char* dA = lAb + (p ^ 1) * 16896;
      char* dB = lBb + (p ^ 1) * 49152;
      gl_lds16(aPn + goA[0], dA + (wave * 2 + 0) * 1024);
      gl_lds16(aPn + goA[1], dA + (wave * 2 + 1) * 1024);
      if (lane < 4) gl_lds16(aPn + goAt, dA + 16384 + wave * 64);
#pragma unroll
      for (int j = 0; j < 6; ++j) gl_lds16(bPn + goB[j], dB + (wave + 8 * j) * 1024);
      bPn += 196608;
      if (ayn == 2) { aPn += 2221824; ayn = 0; }  // c++: +2230272 - 2*4224
      else          { aPn += 4224; ++ayn; }
    }

    // one-phase-ahead pipeline; compiler inserts counted lgkm waits per MFMA cluster.
    LOADF(afB, bfB, 1);
    MFMAC(afA, bfA);
    LOADF(afA, bfA, 2);
    MFMAC(afB, bfB);
    MFMAC(afA, bfA);
  }
#undef LOADF
#undef MFMAC

  // ---- epilogue: C frag layout col=lane&15 (jj), row=(lane>>4)*4+v (m) ----
#pragma unroll
  for (int ni = 0; ni < 4; ++ni) {
    const int jj = jj0 + wn * 64 + ni * 16 + lr;
    const int oc = jj >> 2;
    const int py = (jj >> 1) & 1, px = jj & 1;
    const float bv = bias[oc];
#pragma unroll
    for (int mi = 0; mi < 8; ++mi) {
      const int y = y0 + wm * 2 + (mi >> 2);
      const int oy = 2 * y + py;
      const int xb = (mi & 3) * 16 + ((lane >> 4) << 2);
      float* orow = out + ((size_t)(n * 256 + oc) * 128 + oy) * 128;
#pragma unroll
      for (int v = 0; v < 4; ++v) {
        orow[2 * (xb + v) + px] = acc[mi][ni][v] + bv;
      }
    }
  }
}

// ---------------- fallback (ws too small): direct, slow, correct ---------------------
__global__ __launch_bounds__(256) void fallback_k(const float* __restrict__ In,
                                                  const float* __restrict__ W,
                                                  const float* __restrict__ bias,
                                                  float* __restrict__ out) {
  const size_t idx = (size_t)blockIdx.x * 256 + threadIdx.x;
  const int ox = (int)(idx & 127), oy = (int)((idx >> 7) & 127);
  const int oc = (int)((idx >> 14) & 255);
  const int n = (int)(idx >> 22);
  const int px = ox & 1, py = oy & 1;
  const int x = ox >> 1, y = oy >> 1;
  float cy[3][3], cx[3][3];
#pragma unroll
  for (int a = 0; a < 3; ++a)
#pragma unroll
    for (int i = 0; i < 3; ++i) {
      cy[a][i] = c_tab[py][a][i];
      cx[a][i] = c_tab[px][a][i];
    }
  float acc = 0.f;
  const float* wbase = W + (size_t)oc * 2304;
  for (int ic = 0; ic < 256; ++ic) {
    const float* ib = In + (((size_t)(n * 256 + ic)) * 64 + y) * 64 + x;
    float pin[3][3];
#pragma unroll
    for (int ay = 0; ay < 3; ++ay) {
      const int yy = y + ay - 1;
#pragma unroll
      for (int ax = 0; ax < 3; ++ax) {
        const int xx = x + ax - 1;
        pin[ay][ax] = (yy >= 0 && yy < 64 && xx >= 0 && xx < 64)
                          ? ib[(ay - 1) * 64 + (ax - 1)] : 0.f;
      }
    }
    const float* w = wbase + ic * 9;
    float U[3][3];
#pragma unroll
    for (int ay = 0; ay < 3; ++ay)
#pragma unroll
      for (int ix = 0; ix < 3; ++ix)
        U[ay][ix] = cx[0][ix] * pin[ay][0] + cx[1][ix] * pin[ay][1] + cx[2][ix] * pin[ay][2];
#pragma unroll
    for (int iy = 0; iy < 3; ++iy)
#pragma unroll
      for (int ix = 0; ix < 3; ++ix) {
        const float V = cy[0][iy] * U[0][ix] + cy[1][iy] * U[1][ix] + cy[2][iy] * U[2][ix];
        acc += w[iy * 3 + ix] * V;
      }
  }
  out[idx] = acc + bias[oc];
}

extern "C" void kernel_launch(void* const* d_in, const int* in_sizes, int n_in,
                              void* d_out, int out_size, void* d_ws, size_t ws_size,
                              hipStream_t stream) {
  const float* In = (const float*)d_in[0];    // [8][256][64][64]
  const float* W = (const float*)d_in[1];     // [256][256][3][3]
  const float* bias = (const float*)d_in[2];  // [256]
  float* out = (float*)d_out;                 // [8][256][128][128]

  const size_t E_BYTES = (size_t)1024 * 2304 * 2;       // 4,718,592
  const size_t A_BYTES = (size_t)8 * 66 * 66 * 256 * 2; // 17,842,176

  if (ws_size >= E_BYTES + A_BYTES) {
    f16* Et = (f16*)d_ws;
    f16* Ah = (f16*)((char*)d_ws + E_BYTES);
    prep_k<<<256 + 4224, 256, 0, stream>>>(W, In, Et, Ah);
    gemm_k<<<512, 512, 0, stream>>>(Ah, Et, bias, out);
  } else {
    fallback_k<<<131072, 256, 0, stream>>>(In, W, bias, out);
  }
}